// Round 9
// baseline (376.437 us; speedup 1.0000x reference)
//
#include <hip/hip_runtime.h>

typedef unsigned short u16;
typedef __bf16 bf16x8 __attribute__((ext_vector_type(8)));
typedef float f32x4 __attribute__((ext_vector_type(4)));

#define BB 2
#define TT 2048
#define CC 1024
#define HH 16
#define DD 64
#define MM (BB*TT)   // 4096

__device__ __forceinline__ u16 f2b(float f) {
    union { float f; unsigned int i; } a; a.f = f;
    unsigned int u = a.i;
    unsigned int r = (u + 0x7FFFu + ((u >> 16) & 1u)) >> 16;
    return (u16)r;
}
__device__ __forceinline__ u16 f2b_fast(float f) {
    union { float f; unsigned int i; } a; a.f = f;
    return (u16)((a.i + 0x8000u) >> 16);
}

// async global -> LDS, 16B per lane (dest = wave-uniform base + lane*16)
__device__ __forceinline__ void gld16(const u16* g, u16* l) {
    __builtin_amdgcn_global_load_lds(
        (const __attribute__((address_space(1))) unsigned int*)g,
        (__attribute__((address_space(3))) unsigned int*)l, 16, 0, 0);
}

// ---------------- fp32 -> bf16 elementwise ----------------
__global__ __launch_bounds__(256) void cvt_x_k(const float* __restrict__ in,
                                               u16* __restrict__ out) {
    int i = blockIdx.x * 256 + threadIdx.x;
    float4 v = ((const float4*)in)[i];
    ushort4 o;
    o.x = f2b(v.x); o.y = f2b(v.y); o.z = f2b(v.z); o.w = f2b(v.w);
    ((ushort4*)out)[i] = o;
}

// ------ fp32 [K,N] -> bf16 [N,K] transpose+convert ------
__global__ __launch_bounds__(256) void transpose_cvt_k(const float* __restrict__ in,
                                                       u16* __restrict__ out,
                                                       int K, int N) {
    __shared__ u16 tile[64][65];
    int n0 = blockIdx.x * 64, k0 = blockIdx.y * 64;
    int tx = threadIdx.x, ty = threadIdx.y;   // (64,4)
    for (int i = 0; i < 16; i++) {
        int row = ty + i * 4;
        tile[row][tx] = f2b(in[(size_t)(k0 + row) * N + n0 + tx]);
    }
    __syncthreads();
    for (int i = 0; i < 16; i++) {
        int row = ty + i * 4;
        out[(size_t)(n0 + row) * K + k0 + tx] = tile[tx][row];
    }
}

// ------ bf16 per-bh transpose: v[bh][T][D] -> vt[bh][D][T] ------
__global__ __launch_bounds__(256) void transpose_v_k(const u16* __restrict__ in,
                                                     u16* __restrict__ out) {
    __shared__ u16 tile[64][65];
    int t0 = blockIdx.x * 64, bh = blockIdx.y;
    const u16* src = in + (size_t)bh * TT * DD;
    u16* dst = out + (size_t)bh * DD * TT;
    int tx = threadIdx.x, ty = threadIdx.y;
    for (int i = 0; i < 16; i++) {
        int row = ty + i * 4;
        tile[row][tx] = src[(size_t)(t0 + row) * DD + tx];
    }
    __syncthreads();
    for (int i = 0; i < 16; i++) {
        int row = ty + i * 4;
        dst[(size_t)row * TT + t0 + tx] = tile[tx][row];
    }
}

// ---------------- GEMM: C[M,N] = A[M,K] * Bt[N,K]^T ----------------
// A is plain row-major [M,K] in both modes.
// MODE 0: scatter C -> q/k/v [B*H, T, D] bf16, q pre-scaled by 0.125*log2(e).
// MODE 1: C -> out [M,N] fp32.
template<int MODE>
__global__ __launch_bounds__(256) void gemm_k(const u16* __restrict__ A,
                                              const u16* __restrict__ Bt,
                                              u16* __restrict__ Cq,
                                              u16* __restrict__ Ck,
                                              u16* __restrict__ Cv,
                                              float* __restrict__ Cout,
                                              int N, int K) {
    __shared__ __attribute__((aligned(16))) u16 As[128 * 32];
    __shared__ __attribute__((aligned(16))) u16 Bs[128 * 32];
    const int tid  = threadIdx.x;
    const int lane = tid & 63, w = tid >> 6;
    const int wm = w >> 1, wn = w & 1;
    const int quad = lane >> 4, l16 = lane & 15;
    const int m0 = blockIdx.x * 128, n0 = blockIdx.y * 128;

    f32x4 acc[4][4];
    for (int mi = 0; mi < 4; mi++)
        for (int ni = 0; ni < 4; ni++)
            for (int e = 0; e < 4; e++) acc[mi][ni][e] = 0.f;

    for (int k0 = 0; k0 < K; k0 += 32) {
        for (int i = 0; i < 2; i++) {
            int c = tid + 256 * i;
            int row = c >> 2, col = (c & 3) * 8;
            gld16(A + (size_t)(m0 + row) * K + k0 + col, &As[c * 8]);
            gld16(Bt + (size_t)(n0 + row) * K + k0 + col, &Bs[c * 8]);
        }
        __syncthreads();
        bf16x8 af[4], bfm[4];
        for (int mi = 0; mi < 4; mi++)
            af[mi] = *(const bf16x8*)&As[(wm * 64 + mi * 16 + l16) * 32 + quad * 8];
        for (int ni = 0; ni < 4; ni++)
            bfm[ni] = *(const bf16x8*)&Bs[(wn * 64 + ni * 16 + l16) * 32 + quad * 8];
        for (int mi = 0; mi < 4; mi++)
            for (int ni = 0; ni < 4; ni++)
                acc[mi][ni] = __builtin_amdgcn_mfma_f32_16x16x32_bf16(
                    af[mi], bfm[ni], acc[mi][ni], 0, 0, 0);
        __syncthreads();
    }

    const float SCQ = 0.125f * 1.44269504f;
    for (int mi = 0; mi < 4; mi++)
        for (int ni = 0; ni < 4; ni++)
            for (int r = 0; r < 4; r++) {
                int row = m0 + wm * 64 + mi * 16 + quad * 4 + r;
                int col = n0 + wn * 64 + ni * 16 + l16;
                if constexpr (MODE == 0) {
                    int which = col >> 10;
                    int h = (col >> 6) & 15, d = col & 63;
                    int b = row >> 11, t = row & 2047;
                    size_t off = ((size_t)(b * HH + h) * TT + t) * DD + d;
                    float val = acc[mi][ni][r];
                    if (which == 0) val *= SCQ;
                    (which == 0 ? Cq : which == 1 ? Ck : Cv)[off] = f2b(val);
                } else {
                    Cout[(size_t)row * N + col] = acc[mi][ni][r];
                }
            }
}

// ---------------- flash attention v6: one wave per 16-row q-chunk ----------------
// 4096 single-wave blocks (64 threads). No pairing: dynamic scheduling over
// [1..16]-pass chunks; heavy chunks dispatched first. No-max exp2 softmax;
// row-sum via MFMA against ones-in-col0; no barriers; Ps (4 KB) per block.
// Q,K: [bh][T][D] bf16 (q pre-scaled); Vt: [bh][D][T]; Y: [B,T,C] bf16.
__global__ __launch_bounds__(64, 4) void attn_k(const u16* __restrict__ Q,
                                                const u16* __restrict__ Kb,
                                                const u16* __restrict__ Vtg,
                                                u16* __restrict__ Y) {
    __shared__ __attribute__((aligned(16))) u16 Ps[16 * 128];   // 4 KB
    const int lane = threadIdx.x;
    const int quad = lane >> 4, l16 = lane & 15;
    const int id  = blockIdx.x;
    const int bh  = id >> 7;
    const int c   = 127 - (id & 127);          // chunk: heavy (late rows) first
    const int t0  = c * 16;
    const int nkt = (c >> 3) + 1;              // 128-wide k-tiles to cover t0+15
    const int diag = c >> 3;
    const size_t base  = (size_t)bh * TT * DD;
    const size_t baseV = (size_t)bh * DD * TT;
    const int bb = bh >> 4, hh = bh & 15;

    // ones B-frag: B[k][n] = (n==0) ? 1 : 0  ->  D[m][0] = rowsum(P[m][:])
    bf16x8 onesf;
    {
        __bf16 one = (__bf16)1.0f, zero = (__bf16)0.0f;
        __bf16 v = (l16 == 0) ? one : zero;
        for (int j = 0; j < 8; j++) onesf[j] = v;
    }

    // Q fragments (A-layout, pre-scaled by 0.125*log2e in gemm0 epilogue)
    bf16x8 qf[2];
    for (int kk = 0; kk < 2; kk++)
        qf[kk] = *(const bf16x8*)(Q + base +
            (size_t)(t0 + l16) * DD + kk * 32 + quad * 8);

    f32x4 oacc[4], lacc;
    for (int nd = 0; nd < 4; nd++)
        for (int e = 0; e < 4; e++) oacc[nd][e] = 0.f;
    for (int e = 0; e < 4; e++) lacc[e] = 0.f;

    for (int jk = 0; jk < nkt; jk++) {
        const u16* kb = Kb + base + (size_t)(jk * 128) * DD;
        const u16* vb = Vtg + baseV + jk * 128;

        // S = q K^T (16 x 128), kf loaded in two batches of 8
        f32x4 s[8];
        for (int ni = 0; ni < 8; ni++)
            for (int e = 0; e < 4; e++) s[ni][e] = 0.f;
        for (int kk = 0; kk < 2; kk++) {
            bf16x8 kfa[8];
            for (int ni = 0; ni < 8; ni++)
                kfa[ni] = *(const bf16x8*)(kb +
                    (size_t)(ni * 16 + l16) * DD + kk * 32 + quad * 8);
            for (int ni = 0; ni < 8; ni++)
                s[ni] = __builtin_amdgcn_mfma_f32_16x16x32_bf16(
                    qf[kk], kfa[ni], s[ni], 0, 0, 0);
        }

        // mask (diag tile only) -> exp2 -> pack -> Ps (per-wave, no barrier)
        if (jk == diag) {
            int row0 = t0 + quad * 4;
            int col0 = jk * 128 + l16;
            for (int ni = 0; ni < 8; ni++)
                for (int r = 0; r < 4; r++)
                    if (col0 + ni * 16 > row0 + r) s[ni][r] = -1e30f;
        }
        for (int ni = 0; ni < 8; ni++)
            for (int r = 0; r < 4; r++) {
                float pv = __builtin_amdgcn_exp2f(s[ni][r]);
                int row = quad * 4 + r;
                int cg  = ni * 2 + (l16 >> 3);
                Ps[row * 128 + ((cg ^ row) << 3) + (l16 & 7)] = f2b_fast(pv);
            }

        // O += P V ; l += P * ones
        for (int kk = 0; kk < 4; kk++) {
            bf16x8 vfa[4];
            for (int nd = 0; nd < 4; nd++)
                vfa[nd] = *(const bf16x8*)(vb +
                    (size_t)(nd * 16 + l16) * TT + kk * 32 + quad * 8);
            bf16x8 pf = *(const bf16x8*)&Ps[l16 * 128 +
                (((kk * 4 + quad) ^ l16) << 3)];
            for (int nd = 0; nd < 4; nd++)
                oacc[nd] = __builtin_amdgcn_mfma_f32_16x16x32_bf16(
                    pf, vfa[nd], oacc[nd], 0, 0, 0);
            lacc = __builtin_amdgcn_mfma_f32_16x16x32_bf16(
                pf, onesf, lacc, 0, 0, 0);
        }
    }

    // epilogue: broadcast l (col 0 of lacc) and write Y in [B,T,C]
    for (int r = 0; r < 4; r++) {
        float l = __shfl(lacc[r], (lane & 48));   // lane quad*16 (l16==0)
        float linv = 1.0f / l;
        int t = t0 + quad * 4 + r;
        for (int nd = 0; nd < 4; nd++) {
            int col = hh * 64 + nd * 16 + l16;
            Y[((size_t)(bb * TT + t)) * CC + col] = f2b(oacc[nd][r] * linv);
        }
    }
}

extern "C" void kernel_launch(void* const* d_in, const int* in_sizes, int n_in,
                              void* d_out, int out_size, void* d_ws, size_t ws_size,
                              hipStream_t stream) {
    const float* x      = (const float*)d_in[0];   // [2,2048,1024] fp32
    const float* W_attn = (const float*)d_in[1];   // [1024,3072]  fp32
    const float* W_proj = (const float*)d_in[2];   // [1024,1024]  fp32
    float* out = (float*)d_out;                    // [2,2048,1024] fp32

    u16* Wt_attn = (u16*)d_ws;                    // 3072*1024
    u16* Wt_proj = Wt_attn + 3072 * 1024;         // 1024*1024
    u16* xb      = Wt_proj + 1024 * 1024;         // 4096*1024 (reused as vt)
    u16* q       = xb + (size_t)MM * CC;
    u16* k       = q + (size_t)32 * 2048 * 64;
    u16* v       = k + (size_t)32 * 2048 * 64;
    u16* y       = v + (size_t)32 * 2048 * 64;    // [B,T,C] bf16
    u16* vt      = xb;                            // dead after gemm<0>

    cvt_x_k<<<dim3(MM * CC / 1024), 256, 0, stream>>>(x, xb);
    transpose_cvt_k<<<dim3(3072 / 64, 1024 / 64), dim3(64, 4), 0, stream>>>(
        W_attn, Wt_attn, 1024, 3072);
    transpose_cvt_k<<<dim3(1024 / 64, 1024 / 64), dim3(64, 4), 0, stream>>>(
        W_proj, Wt_proj, 1024, 1024);
    gemm_k<0><<<dim3(MM / 128, 3072 / 128), 256, 0, stream>>>(
        xb, Wt_attn, q, k, v, nullptr, 3072, 1024);
    transpose_v_k<<<dim3(TT / 64, BB * HH), dim3(64, 4), 0, stream>>>(v, vt);
    attn_k<<<dim3(4096), 64, 0, stream>>>(q, k, vt, y);
    gemm_k<1><<<dim3(MM / 128, 1024 / 128), 256, 0, stream>>>(
        y, Wt_proj, nullptr, nullptr, nullptr, out, 1024, 1024);
}

// Round 10
// 313.331 us; speedup vs baseline: 1.2014x; 1.2014x over previous
//
#include <hip/hip_runtime.h>

typedef unsigned short u16;
typedef __bf16 bf16x8 __attribute__((ext_vector_type(8)));
typedef float f32x4 __attribute__((ext_vector_type(4)));

#define BB 2
#define TT 2048
#define CC 1024
#define HH 16
#define DD 64
#define MM (BB*TT)   // 4096

__device__ __forceinline__ u16 f2b(float f) {
    union { float f; unsigned int i; } a; a.f = f;
    unsigned int u = a.i;
    unsigned int r = (u + 0x7FFFu + ((u >> 16) & 1u)) >> 16;
    return (u16)r;
}
__device__ __forceinline__ u16 f2b_fast(float f) {
    union { float f; unsigned int i; } a; a.f = f;
    return (u16)((a.i + 0x8000u) >> 16);
}

// async global -> LDS, 16B per lane (dest = wave-uniform base + lane*16)
__device__ __forceinline__ void gld16(const u16* g, u16* l) {
    __builtin_amdgcn_global_load_lds(
        (const __attribute__((address_space(1))) unsigned int*)g,
        (__attribute__((address_space(3))) unsigned int*)l, 16, 0, 0);
}

// ---------------- fp32 -> bf16 elementwise ----------------
__global__ __launch_bounds__(256) void cvt_x_k(const float* __restrict__ in,
                                               u16* __restrict__ out) {
    int i = blockIdx.x * 256 + threadIdx.x;
    float4 v = ((const float4*)in)[i];
    ushort4 o;
    o.x = f2b(v.x); o.y = f2b(v.y); o.z = f2b(v.z); o.w = f2b(v.w);
    ((ushort4*)out)[i] = o;
}

// ------ fp32 [K,N] -> bf16 [N,K] transpose+convert ------
__global__ __launch_bounds__(256) void transpose_cvt_k(const float* __restrict__ in,
                                                       u16* __restrict__ out,
                                                       int K, int N) {
    __shared__ u16 tile[64][65];
    int n0 = blockIdx.x * 64, k0 = blockIdx.y * 64;
    int tx = threadIdx.x, ty = threadIdx.y;   // (64,4)
    for (int i = 0; i < 16; i++) {
        int row = ty + i * 4;
        tile[row][tx] = f2b(in[(size_t)(k0 + row) * N + n0 + tx]);
    }
    __syncthreads();
    for (int i = 0; i < 16; i++) {
        int row = ty + i * 4;
        out[(size_t)(n0 + row) * K + k0 + tx] = tile[tx][row];
    }
}

// ------ bf16 per-bh transpose: v[bh][T][D] -> vt[bh][D][T] ------
__global__ __launch_bounds__(256) void transpose_v_k(const u16* __restrict__ in,
                                                     u16* __restrict__ out) {
    __shared__ u16 tile[64][65];
    int t0 = blockIdx.x * 64, bh = blockIdx.y;
    const u16* src = in + (size_t)bh * TT * DD;
    u16* dst = out + (size_t)bh * DD * TT;
    int tx = threadIdx.x, ty = threadIdx.y;
    for (int i = 0; i < 16; i++) {
        int row = ty + i * 4;
        tile[row][tx] = src[(size_t)(t0 + row) * DD + tx];
    }
    __syncthreads();
    for (int i = 0; i < 16; i++) {
        int row = ty + i * 4;
        dst[(size_t)row * TT + t0 + tx] = tile[tx][row];
    }
}

// ---------------- GEMM: C[M,N] = A[M,K] * Bt[N,K]^T ----------------
// A is plain row-major [M,K] in both modes.
// MODE 0: scatter C -> q/k/v [B*H, T, D] bf16, q pre-scaled by 0.125*log2(e).
// MODE 1: C -> out [M,N] fp32.
template<int MODE>
__global__ __launch_bounds__(256) void gemm_k(const u16* __restrict__ A,
                                              const u16* __restrict__ Bt,
                                              u16* __restrict__ Cq,
                                              u16* __restrict__ Ck,
                                              u16* __restrict__ Cv,
                                              float* __restrict__ Cout,
                                              int N, int K) {
    __shared__ __attribute__((aligned(16))) u16 As[128 * 32];
    __shared__ __attribute__((aligned(16))) u16 Bs[128 * 32];
    const int tid  = threadIdx.x;
    const int lane = tid & 63, w = tid >> 6;
    const int wm = w >> 1, wn = w & 1;
    const int quad = lane >> 4, l16 = lane & 15;
    const int m0 = blockIdx.x * 128, n0 = blockIdx.y * 128;

    f32x4 acc[4][4];
    for (int mi = 0; mi < 4; mi++)
        for (int ni = 0; ni < 4; ni++)
            for (int e = 0; e < 4; e++) acc[mi][ni][e] = 0.f;

    for (int k0 = 0; k0 < K; k0 += 32) {
        for (int i = 0; i < 2; i++) {
            int c = tid + 256 * i;
            int row = c >> 2, col = (c & 3) * 8;
            gld16(A + (size_t)(m0 + row) * K + k0 + col, &As[c * 8]);
            gld16(Bt + (size_t)(n0 + row) * K + k0 + col, &Bs[c * 8]);
        }
        __syncthreads();
        bf16x8 af[4], bfm[4];
        for (int mi = 0; mi < 4; mi++)
            af[mi] = *(const bf16x8*)&As[(wm * 64 + mi * 16 + l16) * 32 + quad * 8];
        for (int ni = 0; ni < 4; ni++)
            bfm[ni] = *(const bf16x8*)&Bs[(wn * 64 + ni * 16 + l16) * 32 + quad * 8];
        for (int mi = 0; mi < 4; mi++)
            for (int ni = 0; ni < 4; ni++)
                acc[mi][ni] = __builtin_amdgcn_mfma_f32_16x16x32_bf16(
                    af[mi], bfm[ni], acc[mi][ni], 0, 0, 0);
        __syncthreads();
    }

    const float SCQ = 0.125f * 1.44269504f;
    for (int mi = 0; mi < 4; mi++)
        for (int ni = 0; ni < 4; ni++)
            for (int r = 0; r < 4; r++) {
                int row = m0 + wm * 64 + mi * 16 + quad * 4 + r;
                int col = n0 + wn * 64 + ni * 16 + l16;
                if constexpr (MODE == 0) {
                    int which = col >> 10;
                    int h = (col >> 6) & 15, d = col & 63;
                    int b = row >> 11, t = row & 2047;
                    size_t off = ((size_t)(b * HH + h) * TT + t) * DD + d;
                    float val = acc[mi][ni][r];
                    if (which == 0) val *= SCQ;
                    (which == 0 ? Cq : which == 1 ? Ck : Cv)[off] = f2b(val);
                } else {
                    Cout[(size_t)row * N + col] = acc[mi][ni][r];
                }
            }
}

// ---------------- flash attention v7: 4-wave blocks, 1024 of them ----------------
// Block = one 64-row q-tile (4 waves x 16 rows). All 4 waves load identical
// kfa/vfa addresses -> L1 dedup (the v5 sharing, kept). 1024 blocks -> 4
// blocks/CU -> 16 waves/CU TLP. Heavy tiles dispatched first for backfill.
// No-max exp2 softmax; row-sum via VALU accumulation + ONE end shuffle tree.
// No barriers. Q,K: [bh][T][D] (q pre-scaled); Vt: [bh][D][T]; Y: [B,T,C].
__global__ __launch_bounds__(256, 4) void attn_k(const u16* __restrict__ Q,
                                                 const u16* __restrict__ Kb,
                                                 const u16* __restrict__ Vtg,
                                                 u16* __restrict__ Y) {
    __shared__ __attribute__((aligned(16))) u16 Ps[4][16 * 128];   // 16 KB
    const int tid  = threadIdx.x;
    const int lane = tid & 63, w = tid >> 6;
    const int quad = lane >> 4, l16 = lane & 15;
    const int id  = blockIdx.x;
    const int j   = 31 - (id >> 5);            // q-tile: heavy (late rows) first
    const int bh  = id & 31;
    const int t0  = j * 64;
    const int nkt  = (j >> 1) + 1;             // 128-wide k-tiles to cover t0+63
    const int diag = j >> 1;
    const size_t base  = (size_t)bh * TT * DD;
    const size_t baseV = (size_t)bh * DD * TT;
    const int bb = bh >> 4, hh = bh & 15;

    // Q fragments (A-layout; rows t0 + w*16 + l16), pre-scaled by 0.125*log2e
    bf16x8 qf[2];
    for (int kk = 0; kk < 2; kk++)
        qf[kk] = *(const bf16x8*)(Q + base +
            (size_t)(t0 + w * 16 + l16) * DD + kk * 32 + quad * 8);

    f32x4 oacc[4];
    float rsum[4] = {0.f, 0.f, 0.f, 0.f};
    for (int nd = 0; nd < 4; nd++)
        for (int e = 0; e < 4; e++) oacc[nd][e] = 0.f;

    for (int jk = 0; jk < nkt; jk++) {
        const u16* kb = Kb + base + (size_t)(jk * 128) * DD;
        const u16* vb = Vtg + baseV + jk * 128;

        // S = q K^T (16 x 128); both kfa batches issued up front (MLP)
        bf16x8 kfa0[8], kfa1[8];
        for (int ni = 0; ni < 8; ni++)
            kfa0[ni] = *(const bf16x8*)(kb + (size_t)(ni * 16 + l16) * DD + quad * 8);
        for (int ni = 0; ni < 8; ni++)
            kfa1[ni] = *(const bf16x8*)(kb + (size_t)(ni * 16 + l16) * DD + 32 + quad * 8);

        f32x4 s[8];
        for (int ni = 0; ni < 8; ni++)
            for (int e = 0; e < 4; e++) s[ni][e] = 0.f;
        for (int ni = 0; ni < 8; ni++)
            s[ni] = __builtin_amdgcn_mfma_f32_16x16x32_bf16(qf[0], kfa0[ni], s[ni], 0, 0, 0);
        for (int ni = 0; ni < 8; ni++)
            s[ni] = __builtin_amdgcn_mfma_f32_16x16x32_bf16(qf[1], kfa1[ni], s[ni], 0, 0, 0);

        // mask (diag tile only) -> exp2 -> rowsum (VALU) -> pack -> Ps
        if (jk == diag) {
            int row0 = t0 + w * 16 + quad * 4;
            int col0 = jk * 128 + l16;
            for (int ni = 0; ni < 8; ni++)
                for (int r = 0; r < 4; r++)
                    if (col0 + ni * 16 > row0 + r) s[ni][r] = -1e30f;
        }
        for (int ni = 0; ni < 8; ni++)
            for (int r = 0; r < 4; r++) {
                float pv = __builtin_amdgcn_exp2f(s[ni][r]);
                rsum[r] += pv;
                int row = quad * 4 + r;
                int cg  = ni * 2 + (l16 >> 3);
                Ps[w][row * 128 + ((cg ^ row) << 3) + (l16 & 7)] = f2b_fast(pv);
            }

        // O += P V (Ps per-wave: no barrier; loads independent across kk)
        for (int kk = 0; kk < 4; kk++) {
            bf16x8 vfa[4];
            for (int nd = 0; nd < 4; nd++)
                vfa[nd] = *(const bf16x8*)(vb +
                    (size_t)(nd * 16 + l16) * TT + kk * 32 + quad * 8);
            bf16x8 pf = *(const bf16x8*)&Ps[w][l16 * 128 +
                (((kk * 4 + quad) ^ l16) << 3)];
            for (int nd = 0; nd < 4; nd++)
                oacc[nd] = __builtin_amdgcn_mfma_f32_16x16x32_bf16(
                    pf, vfa[nd], oacc[nd], 0, 0, 0);
        }
    }

    // single end-of-kernel row-sum reduction (16-lane groups) + write [B,T,C]
    for (int r = 0; r < 4; r++) {
        float sm = rsum[r];
        for (int off = 8; off >= 1; off >>= 1)
            sm += __shfl_xor(sm, off);
        float linv = 1.0f / sm;
        int t = t0 + w * 16 + quad * 4 + r;
        for (int nd = 0; nd < 4; nd++) {
            int col = hh * 64 + nd * 16 + l16;
            Y[((size_t)(bb * TT + t)) * CC + col] = f2b(oacc[nd][r] * linv);
        }
    }
}

extern "C" void kernel_launch(void* const* d_in, const int* in_sizes, int n_in,
                              void* d_out, int out_size, void* d_ws, size_t ws_size,
                              hipStream_t stream) {
    const float* x      = (const float*)d_in[0];   // [2,2048,1024] fp32
    const float* W_attn = (const float*)d_in[1];   // [1024,3072]  fp32
    const float* W_proj = (const float*)d_in[2];   // [1024,1024]  fp32
    float* out = (float*)d_out;                    // [2,2048,1024] fp32

    u16* Wt_attn = (u16*)d_ws;                    // 3072*1024
    u16* Wt_proj = Wt_attn + 3072 * 1024;         // 1024*1024
    u16* xb      = Wt_proj + 1024 * 1024;         // 4096*1024 (reused as vt)
    u16* q       = xb + (size_t)MM * CC;
    u16* k       = q + (size_t)32 * 2048 * 64;
    u16* v       = k + (size_t)32 * 2048 * 64;
    u16* y       = v + (size_t)32 * 2048 * 64;    // [B,T,C] bf16
    u16* vt      = xb;                            // dead after gemm<0>

    cvt_x_k<<<dim3(MM * CC / 1024), 256, 0, stream>>>(x, xb);
    transpose_cvt_k<<<dim3(3072 / 64, 1024 / 64), dim3(64, 4), 0, stream>>>(
        W_attn, Wt_attn, 1024, 3072);
    transpose_cvt_k<<<dim3(1024 / 64, 1024 / 64), dim3(64, 4), 0, stream>>>(
        W_proj, Wt_proj, 1024, 1024);
    gemm_k<0><<<dim3(MM / 128, 3072 / 128), 256, 0, stream>>>(
        xb, Wt_attn, q, k, v, nullptr, 3072, 1024);
    transpose_v_k<<<dim3(TT / 64, BB * HH), dim3(64, 4), 0, stream>>>(v, vt);
    attn_k<<<dim3(1024), 256, 0, stream>>>(q, k, vt, y);
    gemm_k<1><<<dim3(MM / 128, 1024 / 128), 256, 0, stream>>>(
        y, Wt_proj, nullptr, nullptr, nullptr, out, 1024, 1024);
}

// Round 11
// 312.745 us; speedup vs baseline: 1.2037x; 1.0019x over previous
//
#include <hip/hip_runtime.h>

typedef unsigned short u16;
typedef __bf16 bf16x8 __attribute__((ext_vector_type(8)));
typedef float f32x4 __attribute__((ext_vector_type(4)));

#define BB 2
#define TT 2048
#define CC 1024
#define HH 16
#define DD 64
#define MM (BB*TT)   // 4096

__device__ __forceinline__ u16 f2b(float f) {
    union { float f; unsigned int i; } a; a.f = f;
    unsigned int u = a.i;
    unsigned int r = (u + 0x7FFFu + ((u >> 16) & 1u)) >> 16;
    return (u16)r;
}
__device__ __forceinline__ u16 f2b_fast(float f) {
    union { float f; unsigned int i; } a; a.f = f;
    return (u16)((a.i + 0x8000u) >> 16);
}

// async global -> LDS, 16B per lane (dest = wave-uniform base + lane*16)
__device__ __forceinline__ void gld16(const u16* g, u16* l) {
    __builtin_amdgcn_global_load_lds(
        (const __attribute__((address_space(1))) unsigned int*)g,
        (__attribute__((address_space(3))) unsigned int*)l, 16, 0, 0);
}

// ---------------- fp32 -> bf16 elementwise ----------------
__global__ __launch_bounds__(256) void cvt_x_k(const float* __restrict__ in,
                                               u16* __restrict__ out) {
    int i = blockIdx.x * 256 + threadIdx.x;
    float4 v = ((const float4*)in)[i];
    ushort4 o;
    o.x = f2b(v.x); o.y = f2b(v.y); o.z = f2b(v.z); o.w = f2b(v.w);
    ((ushort4*)out)[i] = o;
}

// ------ fp32 [K,N] -> bf16 [N,K] transpose+convert ------
__global__ __launch_bounds__(256) void transpose_cvt_k(const float* __restrict__ in,
                                                       u16* __restrict__ out,
                                                       int K, int N) {
    __shared__ u16 tile[64][65];
    int n0 = blockIdx.x * 64, k0 = blockIdx.y * 64;
    int tx = threadIdx.x, ty = threadIdx.y;   // (64,4)
    for (int i = 0; i < 16; i++) {
        int row = ty + i * 4;
        tile[row][tx] = f2b(in[(size_t)(k0 + row) * N + n0 + tx]);
    }
    __syncthreads();
    for (int i = 0; i < 16; i++) {
        int row = ty + i * 4;
        out[(size_t)(n0 + row) * K + k0 + tx] = tile[tx][row];
    }
}

// ------ bf16 per-bh transpose: v[bh][T][D] -> vt[bh][D][T] ------
__global__ __launch_bounds__(256) void transpose_v_k(const u16* __restrict__ in,
                                                     u16* __restrict__ out) {
    __shared__ u16 tile[64][65];
    int t0 = blockIdx.x * 64, bh = blockIdx.y;
    const u16* src = in + (size_t)bh * TT * DD;
    u16* dst = out + (size_t)bh * DD * TT;
    int tx = threadIdx.x, ty = threadIdx.y;
    for (int i = 0; i < 16; i++) {
        int row = ty + i * 4;
        tile[row][tx] = src[(size_t)(t0 + row) * DD + tx];
    }
    __syncthreads();
    for (int i = 0; i < 16; i++) {
        int row = ty + i * 4;
        dst[(size_t)row * TT + t0 + tx] = tile[tx][row];
    }
}

// ---------------- GEMM: C[M,N] = A[M,K] * Bt[N,K]^T ----------------
// A is plain row-major [M,K] in both modes.
// MODE 0: scatter C -> q/k/v [B*H, T, D] bf16, q pre-scaled by 0.125*log2(e).
// MODE 1: C -> out [M,N] fp32.
template<int MODE>
__global__ __launch_bounds__(256) void gemm_k(const u16* __restrict__ A,
                                              const u16* __restrict__ Bt,
                                              u16* __restrict__ Cq,
                                              u16* __restrict__ Ck,
                                              u16* __restrict__ Cv,
                                              float* __restrict__ Cout,
                                              int N, int K) {
    __shared__ __attribute__((aligned(16))) u16 As[128 * 32];
    __shared__ __attribute__((aligned(16))) u16 Bs[128 * 32];
    const int tid  = threadIdx.x;
    const int lane = tid & 63, w = tid >> 6;
    const int wm = w >> 1, wn = w & 1;
    const int quad = lane >> 4, l16 = lane & 15;
    const int m0 = blockIdx.x * 128, n0 = blockIdx.y * 128;

    f32x4 acc[4][4];
    for (int mi = 0; mi < 4; mi++)
        for (int ni = 0; ni < 4; ni++)
            for (int e = 0; e < 4; e++) acc[mi][ni][e] = 0.f;

    for (int k0 = 0; k0 < K; k0 += 32) {
        for (int i = 0; i < 2; i++) {
            int c = tid + 256 * i;
            int row = c >> 2, col = (c & 3) * 8;
            gld16(A + (size_t)(m0 + row) * K + k0 + col, &As[c * 8]);
            gld16(Bt + (size_t)(n0 + row) * K + k0 + col, &Bs[c * 8]);
        }
        __syncthreads();
        bf16x8 af[4], bfm[4];
        for (int mi = 0; mi < 4; mi++)
            af[mi] = *(const bf16x8*)&As[(wm * 64 + mi * 16 + l16) * 32 + quad * 8];
        for (int ni = 0; ni < 4; ni++)
            bfm[ni] = *(const bf16x8*)&Bs[(wn * 64 + ni * 16 + l16) * 32 + quad * 8];
        for (int mi = 0; mi < 4; mi++)
            for (int ni = 0; ni < 4; ni++)
                acc[mi][ni] = __builtin_amdgcn_mfma_f32_16x16x32_bf16(
                    af[mi], bfm[ni], acc[mi][ni], 0, 0, 0);
        __syncthreads();
    }

    const float SCQ = 0.125f * 1.44269504f;
    for (int mi = 0; mi < 4; mi++)
        for (int ni = 0; ni < 4; ni++)
            for (int r = 0; r < 4; r++) {
                int row = m0 + wm * 64 + mi * 16 + quad * 4 + r;
                int col = n0 + wn * 64 + ni * 16 + l16;
                if constexpr (MODE == 0) {
                    int which = col >> 10;
                    int h = (col >> 6) & 15, d = col & 63;
                    int b = row >> 11, t = row & 2047;
                    size_t off = ((size_t)(b * HH + h) * TT + t) * DD + d;
                    float val = acc[mi][ni][r];
                    if (which == 0) val *= SCQ;
                    (which == 0 ? Cq : which == 1 ? Ck : Cv)[off] = f2b(val);
                } else {
                    Cout[(size_t)row * N + col] = acc[mi][ni][r];
                }
            }
}

// ---------------- flash attention v8: v7 minus the register spill ----------------
// Block = one 64-row q-tile (4 waves x 16 rows), 1024 blocks -> 4 blocks/CU.
// kfa loaded PER kk batch (32 VGPRs live, v5's proven pressure) so the body
// fits the 128-VGPR cap of 4 waves/EU with NO scratch spill.
// No-max exp2 softmax; end-only row-sum reduction; no barriers.
// Q,K: [bh][T][D] (q pre-scaled); Vt: [bh][D][T]; Y: [B,T,C].
__global__ __launch_bounds__(256, 4) void attn_k(const u16* __restrict__ Q,
                                                 const u16* __restrict__ Kb,
                                                 const u16* __restrict__ Vtg,
                                                 u16* __restrict__ Y) {
    __shared__ __attribute__((aligned(16))) u16 Ps[4][16 * 128];   // 16 KB
    const int tid  = threadIdx.x;
    const int lane = tid & 63, w = tid >> 6;
    const int quad = lane >> 4, l16 = lane & 15;
    const int id  = blockIdx.x;
    const int j   = 31 - (id >> 5);            // q-tile: heavy (late rows) first
    const int bh  = id & 31;
    const int t0  = j * 64;
    const int nkt  = (j >> 1) + 1;             // 128-wide k-tiles to cover t0+63
    const int diag = j >> 1;
    const size_t base  = (size_t)bh * TT * DD;
    const size_t baseV = (size_t)bh * DD * TT;
    const int bb = bh >> 4, hh = bh & 15;

    // Q fragments (A-layout; rows t0 + w*16 + l16), pre-scaled by 0.125*log2e
    bf16x8 qf[2];
    for (int kk = 0; kk < 2; kk++)
        qf[kk] = *(const bf16x8*)(Q + base +
            (size_t)(t0 + w * 16 + l16) * DD + kk * 32 + quad * 8);

    f32x4 oacc[4];
    float rsum[4] = {0.f, 0.f, 0.f, 0.f};
    for (int nd = 0; nd < 4; nd++)
        for (int e = 0; e < 4; e++) oacc[nd][e] = 0.f;

    for (int jk = 0; jk < nkt; jk++) {
        const u16* kb = Kb + base + (size_t)(jk * 128) * DD;
        const u16* vb = Vtg + baseV + jk * 128;

        // S = q K^T (16 x 128); kfa loaded per kk batch (bounded pressure)
        f32x4 s[8];
        for (int ni = 0; ni < 8; ni++)
            for (int e = 0; e < 4; e++) s[ni][e] = 0.f;
        for (int kk = 0; kk < 2; kk++) {
            bf16x8 kfa[8];
            for (int ni = 0; ni < 8; ni++)
                kfa[ni] = *(const bf16x8*)(kb +
                    (size_t)(ni * 16 + l16) * DD + kk * 32 + quad * 8);
            for (int ni = 0; ni < 8; ni++)
                s[ni] = __builtin_amdgcn_mfma_f32_16x16x32_bf16(
                    qf[kk], kfa[ni], s[ni], 0, 0, 0);
        }

        // mask (diag tile only) -> exp2 -> rowsum (VALU) -> pack -> Ps
        if (jk == diag) {
            int row0 = t0 + w * 16 + quad * 4;
            int col0 = jk * 128 + l16;
            for (int ni = 0; ni < 8; ni++)
                for (int r = 0; r < 4; r++)
                    if (col0 + ni * 16 > row0 + r) s[ni][r] = -1e30f;
        }
        for (int ni = 0; ni < 8; ni++)
            for (int r = 0; r < 4; r++) {
                float pv = __builtin_amdgcn_exp2f(s[ni][r]);
                rsum[r] += pv;
                int row = quad * 4 + r;
                int cg  = ni * 2 + (l16 >> 3);
                Ps[w][row * 128 + ((cg ^ row) << 3) + (l16 & 7)] = f2b_fast(pv);
            }

        // O += P V (Ps per-wave: no barrier; loads independent across kk)
        for (int kk = 0; kk < 4; kk++) {
            bf16x8 vfa[4];
            for (int nd = 0; nd < 4; nd++)
                vfa[nd] = *(const bf16x8*)(vb +
                    (size_t)(nd * 16 + l16) * TT + kk * 32 + quad * 8);
            bf16x8 pf = *(const bf16x8*)&Ps[w][l16 * 128 +
                (((kk * 4 + quad) ^ l16) << 3)];
            for (int nd = 0; nd < 4; nd++)
                oacc[nd] = __builtin_amdgcn_mfma_f32_16x16x32_bf16(
                    pf, vfa[nd], oacc[nd], 0, 0, 0);
        }
    }

    // single end-of-kernel row-sum reduction (16-lane groups) + write [B,T,C]
    for (int r = 0; r < 4; r++) {
        float sm = rsum[r];
        for (int off = 8; off >= 1; off >>= 1)
            sm += __shfl_xor(sm, off);
        float linv = 1.0f / sm;
        int t = t0 + w * 16 + quad * 4 + r;
        for (int nd = 0; nd < 4; nd++) {
            int col = hh * 64 + nd * 16 + l16;
            Y[((size_t)(bb * TT + t)) * CC + col] = f2b(oacc[nd][r] * linv);
        }
    }
}

extern "C" void kernel_launch(void* const* d_in, const int* in_sizes, int n_in,
                              void* d_out, int out_size, void* d_ws, size_t ws_size,
                              hipStream_t stream) {
    const float* x      = (const float*)d_in[0];   // [2,2048,1024] fp32
    const float* W_attn = (const float*)d_in[1];   // [1024,3072]  fp32
    const float* W_proj = (const float*)d_in[2];   // [1024,1024]  fp32
    float* out = (float*)d_out;                    // [2,2048,1024] fp32

    u16* Wt_attn = (u16*)d_ws;                    // 3072*1024
    u16* Wt_proj = Wt_attn + 3072 * 1024;         // 1024*1024
    u16* xb      = Wt_proj + 1024 * 1024;         // 4096*1024 (reused as vt)
    u16* q       = xb + (size_t)MM * CC;
    u16* k       = q + (size_t)32 * 2048 * 64;
    u16* v       = k + (size_t)32 * 2048 * 64;
    u16* y       = v + (size_t)32 * 2048 * 64;    // [B,T,C] bf16
    u16* vt      = xb;                            // dead after gemm<0>

    cvt_x_k<<<dim3(MM * CC / 1024), 256, 0, stream>>>(x, xb);
    transpose_cvt_k<<<dim3(3072 / 64, 1024 / 64), dim3(64, 4), 0, stream>>>(
        W_attn, Wt_attn, 1024, 3072);
    transpose_cvt_k<<<dim3(1024 / 64, 1024 / 64), dim3(64, 4), 0, stream>>>(
        W_proj, Wt_proj, 1024, 1024);
    gemm_k<0><<<dim3(MM / 128, 3072 / 128), 256, 0, stream>>>(
        xb, Wt_attn, q, k, v, nullptr, 3072, 1024);
    transpose_v_k<<<dim3(TT / 64, BB * HH), dim3(64, 4), 0, stream>>>(v, vt);
    attn_k<<<dim3(1024), 256, 0, stream>>>(q, k, vt, y);
    gemm_k<1><<<dim3(MM / 128, 1024 / 128), 256, 0, stream>>>(
        y, Wt_proj, nullptr, nullptr, nullptr, out, 1024, 1024);
}